// Round 13
// baseline (666.895 us; speedup 1.0000x reference)
//
#include <hip/hip_runtime.h>
#include <stdint.h>

typedef unsigned short u16;
typedef float f32x4 __attribute__((ext_vector_type(4)));
typedef float f32x16 __attribute__((ext_vector_type(16)));
typedef __bf16 bf16x8 __attribute__((ext_vector_type(8)));
typedef u16 u16x8 __attribute__((ext_vector_type(8)));
typedef u16 u16x4 __attribute__((ext_vector_type(4)));

#define B_ 4
#define N_ 2048
#define C_ 1024
#define H_ 16
#define D_ 64

__device__ __forceinline__ u16 f2bf(float f) {
  unsigned u = __builtin_bit_cast(unsigned, f);
  u += 0x7FFFu + ((u >> 16) & 1u);
  return (u16)(u >> 16);
}
__device__ __forceinline__ float bf2f(u16 h) {
  unsigned u = ((unsigned)h) << 16;
  return __builtin_bit_cast(float, u);
}
__device__ __forceinline__ f32x4 mfma16(u16x8 a, u16x8 b, f32x4 c) {
  return __builtin_amdgcn_mfma_f32_16x16x32_bf16(
      __builtin_bit_cast(bf16x8, a), __builtin_bit_cast(bf16x8, b), c, 0, 0, 0);
}
__device__ __forceinline__ f32x16 mfma32(u16x8 a, u16x8 b, f32x16 c) {
  return __builtin_amdgcn_mfma_f32_32x32x16_bf16(
      __builtin_bit_cast(bf16x8, a), __builtin_bit_cast(bf16x8, b), c, 0, 0, 0);
}
__device__ __forceinline__ void gload_lds16(const void* g, void* l) {
  __builtin_amdgcn_global_load_lds(
      (const __attribute__((address_space(1))) void*)g,
      (__attribute__((address_space(3))) void*)l, 16, 0, 0);
}
__device__ __forceinline__ float exp2_hw(float x) {
  return __builtin_amdgcn_exp2f(x);
}
__device__ __forceinline__ unsigned cvt_pk_bf16(float lo, float hi) {
  unsigned d;
  asm("v_cvt_pk_bf16_f32 %0, %1, %2" : "=v"(d) : "v"(lo), "v"(hi));
  return d;
}

// ---------------- fp32 -> bf16 convert (3 tensors, one launch) ----------------
__global__ __launch_bounds__(256) void convert_x3(
    const float* __restrict__ a, const float* __restrict__ b,
    const float* __restrict__ c, u16* __restrict__ oa, u16* __restrict__ ob,
    u16* __restrict__ oc) {
  const float* in = blockIdx.y == 0 ? a : (blockIdx.y == 1 ? b : c);
  u16* out = blockIdx.y == 0 ? oa : (blockIdx.y == 1 ? ob : oc);
  int i = blockIdx.x * 256 + threadIdx.x;
  f32x4 v = *(const f32x4*)(in + (size_t)i * 4);
  u16x4 o;
#pragma unroll
  for (int j = 0; j < 4; j++) o[j] = f2bf(v[j]);
  *(u16x4*)(out + (size_t)i * 4) = o;
}

// -------- W [K][N] fp32 -> W^T [N][K] bf16, 4 weights in one launch --------
__global__ __launch_bounds__(256) void transpose_convert_w4(
    const float* __restrict__ w0, const float* __restrict__ w1,
    const float* __restrict__ w2, const float* __restrict__ w3,
    u16* __restrict__ o0, u16* __restrict__ o1, u16* __restrict__ o2,
    u16* __restrict__ o3) {
  const float* in = blockIdx.y == 0 ? w0
                    : blockIdx.y == 1 ? w1
                    : blockIdx.y == 2 ? w2 : w3;
  u16* out = blockIdx.y == 0 ? o0 : blockIdx.y == 1 ? o1 : blockIdx.y == 2 ? o2 : o3;
  __shared__ float tile[64][65];
  const int t = threadIdx.x;
  const int bx = blockIdx.x;
  const int tr = (bx >> 4) << 6;
  const int tc = (bx & 15) << 6;
#pragma unroll
  for (int i = 0; i < 16; i++) {
    int idx = i * 256 + t;
    int rr = idx >> 6, cc = idx & 63;
    tile[rr][cc] = in[(size_t)(tr + rr) * C_ + tc + cc];
  }
  __syncthreads();
#pragma unroll
  for (int i = 0; i < 16; i++) {
    int idx = i * 256 + t;
    int rr = idx >> 6, cc = idx & 63;
    out[(size_t)(tc + rr) * C_ + tr + cc] = f2bf(tile[cc][rr]);
  }
}

// ----- merged QKV GEMM: 128x128x64, BK=64, T2 swizzle (R6-verified loop) -----
__global__ __launch_bounds__(256) void gemm_qkv(
    const u16* __restrict__ Xq, const u16* __restrict__ Xk,
    const u16* __restrict__ Xv, const u16* __restrict__ WqT,
    const u16* __restrict__ WkT, const u16* __restrict__ WvT,
    const float* __restrict__ bq, const float* __restrict__ bk,
    const float* __restrict__ bv_, u16* __restrict__ Qb, u16* __restrict__ Kb,
    u16* __restrict__ VT) {
  __shared__ u16 lA[128 * 64];
  __shared__ u16 lB[128 * 64];

  const int sel = blockIdx.y;
  const u16* A = sel == 0 ? Xq : sel == 1 ? Xk : Xv;
  const u16* BT = sel == 0 ? WqT : sel == 1 ? WkT : WvT;
  const float* bias = sel == 0 ? bq : sel == 1 ? bk : bv_;

  const int K = 1024;
  const int t = threadIdx.x;
  const int w = t >> 6;
  const int lane = t & 63;
  const int g = lane >> 4;
  const int r = lane & 15;
  const int tm = blockIdx.x >> 3;
  const int tn = blockIdx.x & 7;
  const int m0 = tm << 7;
  const int n0 = tn << 7;
  const int wm = (w >> 1) << 6;
  const int wn = (w & 1) << 6;

  const int srow = t >> 3;
  const int scol = ((t & 7) ^ (srow & 7)) << 3;

  f32x4 acc[4][4] = {};

  for (int k0 = 0; k0 < K; k0 += 64) {
    __syncthreads();
    {
      const u16* gA = A + (size_t)(m0 + srow) * K + (k0 + scol);
      const u16* gB = BT + (size_t)(n0 + srow) * K + (k0 + scol);
#pragma unroll
      for (int p = 0; p < 4; p++) {
        gload_lds16(gA + (size_t)(p * 32) * K, (char*)lA + (p << 12) + (w << 10));
        gload_lds16(gB + (size_t)(p * 32) * K, (char*)lB + (p << 12) + (w << 10));
      }
    }
    asm volatile("s_waitcnt vmcnt(0)" ::: "memory");
    __syncthreads();

    const int rx = (r & 7) << 4;
#pragma unroll
    for (int kk = 0; kk < 2; kk++) {
      u16x8 af[4], bfv[4];
#pragma unroll
      for (int i = 0; i < 4; i++) {
        int rowa = wm + i * 16 + r;
        af[i] = *(const u16x8*)((const char*)lA + (rowa << 7) +
                                (((kk << 6) + (g << 4)) ^ rx));
      }
#pragma unroll
      for (int i = 0; i < 4; i++) {
        int rowb = wn + i * 16 + r;
        bfv[i] = *(const u16x8*)((const char*)lB + (rowb << 7) +
                                 (((kk << 6) + (g << 4)) ^ rx));
      }
#pragma unroll
      for (int mi = 0; mi < 4; mi++)
#pragma unroll
        for (int ni = 0; ni < 4; ni++)
          acc[mi][ni] = mfma16(af[mi], bfv[ni], acc[mi][ni]);
    }
  }

  float bv[4];
#pragma unroll
  for (int ni = 0; ni < 4; ni++) bv[ni] = bias[n0 + wn + ni * 16 + r];

  if (sel == 0) {  // Q: [B,H,N,D], scale 1/sqrt(D)
#pragma unroll
    for (int mi = 0; mi < 4; mi++)
#pragma unroll
      for (int ni = 0; ni < 4; ni++)
#pragma unroll
        for (int j = 0; j < 4; j++) {
          int gm = m0 + wm + mi * 16 + g * 4 + j;
          int gn = n0 + wn + ni * 16 + r;
          float v = (acc[mi][ni][j] + bv[ni]) * 0.125f;
          int b = gm >> 11, n = gm & 2047, h = gn >> 6, d = gn & 63;
          Qb[((((size_t)b * H_ + h) * N_ + n) << 6) + d] = f2bf(v);
        }
  } else if (sel == 1) {  // K' fragment-ready
#pragma unroll
    for (int mi = 0; mi < 4; mi++)
#pragma unroll
      for (int ni = 0; ni < 4; ni++)
#pragma unroll
        for (int j = 0; j < 4; j++) {
          int gm = m0 + wm + mi * 16 + g * 4 + j;
          int gn = n0 + wn + ni * 16 + r;
          float v = acc[mi][ni][j] + bv[ni];
          int b = gm >> 11, n = gm & 2047, h = gn >> 6, d = gn & 63;
          size_t off = (((size_t)(b * H_ + h)) << 17) + ((size_t)(n >> 5) << 11) +
                       ((d >> 4) << 9) + ((((d >> 3) & 1) << 5) + (n & 31)) * 8 + (d & 7);
          Kb[off] = f2bf(v);
        }
  } else {  // V' fragment-ready
#pragma unroll
    for (int mi = 0; mi < 4; mi++)
#pragma unroll
      for (int ni = 0; ni < 4; ni++) {
        int gm0 = m0 + wm + mi * 16 + g * 4;
        int gn = n0 + wn + ni * 16 + r;
        int b = gm0 >> 11, n = gm0 & 2047, h = gn >> 6, d = gn & 63;
        size_t off = (((size_t)(b * H_ + h)) << 17) + ((size_t)(n >> 6) << 12) +
                     ((size_t)((d >> 5) * 4 + ((n >> 4) & 3)) << 9) +
                     ((((n >> 3) & 1) << 5) + (d & 31)) * 8 + (n & 7);
        u16x4 pk;
#pragma unroll
        for (int j = 0; j < 4; j++) pk[j] = f2bf(acc[mi][ni][j] + bv[ni]);
        *(u16x4*)&VT[off] = pk;
      }
  }
}

// ------- final projection GEMM: 128x128x64, BK=64, T2 swizzle, fp32 out ------
__global__ __launch_bounds__(256) void gemm_proj(
    const u16* __restrict__ A, const u16* __restrict__ BT,
    const float* __restrict__ bias, float* __restrict__ out) {
  __shared__ u16 lA[128 * 64];
  __shared__ u16 lB[128 * 64];

  const int K = 1024, N = 1024;
  const int t = threadIdx.x;
  const int w = t >> 6;
  const int lane = t & 63;
  const int g = lane >> 4;
  const int r = lane & 15;
  const int tm = blockIdx.x >> 3;
  const int tn = blockIdx.x & 7;
  const int m0 = tm << 7;
  const int n0 = tn << 7;
  const int wm = (w >> 1) << 6;
  const int wn = (w & 1) << 6;

  const int srow = t >> 3;
  const int scol = ((t & 7) ^ (srow & 7)) << 3;

  f32x4 acc[4][4] = {};

  for (int k0 = 0; k0 < K; k0 += 64) {
    __syncthreads();
    {
      const u16* gA = A + (size_t)(m0 + srow) * K + (k0 + scol);
      const u16* gB = BT + (size_t)(n0 + srow) * K + (k0 + scol);
#pragma unroll
      for (int p = 0; p < 4; p++) {
        gload_lds16(gA + (size_t)(p * 32) * K, (char*)lA + (p << 12) + (w << 10));
        gload_lds16(gB + (size_t)(p * 32) * K, (char*)lB + (p << 12) + (w << 10));
      }
    }
    asm volatile("s_waitcnt vmcnt(0)" ::: "memory");
    __syncthreads();

    const int rx = (r & 7) << 4;
#pragma unroll
    for (int kk = 0; kk < 2; kk++) {
      u16x8 af[4], bfv[4];
#pragma unroll
      for (int i = 0; i < 4; i++) {
        int rowa = wm + i * 16 + r;
        af[i] = *(const u16x8*)((const char*)lA + (rowa << 7) +
                                (((kk << 6) + (g << 4)) ^ rx));
      }
#pragma unroll
      for (int i = 0; i < 4; i++) {
        int rowb = wn + i * 16 + r;
        bfv[i] = *(const u16x8*)((const char*)lB + (rowb << 7) +
                                 (((kk << 6) + (g << 4)) ^ rx));
      }
#pragma unroll
      for (int mi = 0; mi < 4; mi++)
#pragma unroll
        for (int ni = 0; ni < 4; ni++)
          acc[mi][ni] = mfma16(af[mi], bfv[ni], acc[mi][ni]);
    }
  }

  float bv[4];
#pragma unroll
  for (int ni = 0; ni < 4; ni++) bv[ni] = bias[n0 + wn + ni * 16 + r];

#pragma unroll
  for (int mi = 0; mi < 4; mi++)
#pragma unroll
    for (int ni = 0; ni < 4; ni++)
#pragma unroll
      for (int j = 0; j < 4; j++) {
        int gm = m0 + wm + mi * 16 + g * 4 + j;
        int gn = n0 + wn + ni * 16 + r;
        out[(size_t)gm * N + gn] = acc[mi][ni][j] + bv[ni];
      }
}

// ---------------- flash attention: K dbuf, V single-buffered, 5 waves/SIMD ----
// R12-verified numerics, unchanged.  Only change: __launch_bounds__(256, 5)
// caps VGPR at ~102 (R12 measured 108 structural) to cross the 512/5 occupancy
// boundary -> 5 waves/SIMD.  Gap is 6 regs; expect reschedule, not spill.
__device__ __forceinline__ void load_k(const u16* __restrict__ Kb, int k0,
                                       int lane, u16x8 (&kf)[8]) {
  const u16* pK = Kb + ((size_t)(k0 >> 5) << 11) + lane * 8;
#pragma unroll
  for (int s = 0; s < 4; s++) {
    kf[s] = *(const u16x8*)(pK + (s << 9));
    kf[4 + s] = *(const u16x8*)(pK + 2048 + (s << 9));
  }
}
__device__ __forceinline__ void load_v(const u16* __restrict__ Vb, int k0,
                                       int lane, u16x8 (&vf)[8]) {
  const u16* pV = Vb + ((size_t)(k0 >> 6) << 12) + ((k0 & 32) ? 256 : 0) + lane * 8;
#pragma unroll
  for (int c = 0; c < 8; c++) vf[c] = *(const u16x8*)(pV + (c << 9));
}

__device__ __forceinline__ void attn_tile(int k0, const float* __restrict__ tbl,
                                          float* __restrict__ xlds,
                                          const u16x8 (&kf)[8], const u16x8 (&vf)[8],
                                          const u16x8 (&qf)[4], f32x16& o0, f32x16& o1,
                                          float& m_e, float& l_run, int ql, int h) {
  const float L2E = 1.44269504088896340736f;
  f32x16 st0 = {}, st1 = {};
#pragma unroll
  for (int s = 0; s < 4; s++) st0 = mfma32(kf[s], qf[s], st0);
#pragma unroll
  for (int s = 0; s < 4; s++) st1 = mfma32(kf[4 + s], qf[s], st1);

  float e0[16], e1[16];
#pragma unroll
  for (int g2 = 0; g2 < 4; g2++) {
    f32x4 t0 = *(const f32x4*)&tbl[k0 + 8 * g2 + 4 * h];
    f32x4 t1 = *(const f32x4*)&tbl[k0 + 32 + 8 * g2 + 4 * h];
#pragma unroll
    for (int jj = 0; jj < 4; jj++) {
      e0[g2 * 4 + jj] = fmaf(st0[g2 * 4 + jj], L2E, t0[jj]);
      e1[g2 * 4 + jj] = fmaf(st1[g2 * 4 + jj], L2E, t1[jj]);
    }
  }
  float mx[8];
#pragma unroll
  for (int j = 0; j < 8; j++)
    mx[j] = fmaxf(fmaxf(e0[j], e0[j + 8]), fmaxf(e1[j], e1[j + 8]));
#pragma unroll
  for (int j = 0; j < 4; j++) mx[j] = fmaxf(mx[j], mx[j + 4]);
  float pmax = fmaxf(fmaxf(mx[0], mx[1]), fmaxf(mx[2], mx[3]));
  pmax = fmaxf(pmax, __shfl_xor(pmax, 32));

  if (!__all(pmax <= m_e + 8.0f)) {
    float m_new = fmaxf(m_e, pmax);
    float resc = exp2_hw(m_e - m_new);
    xlds[ql] = resc;
#pragma unroll
    for (int g2 = 0; g2 < 4; g2++) {
      f32x4 r4 = *(const f32x4*)&xlds[8 * g2 + 4 * h];
#pragma unroll
      for (int jj = 0; jj < 4; jj++) {
        o0[g2 * 4 + jj] *= r4[jj];
        o1[g2 * 4 + jj] *= r4[jj];
      }
    }
    l_run *= resc;
    m_e = m_new;
  }

#pragma unroll
  for (int j = 0; j < 16; j++) e0[j] = exp2_hw(e0[j] - m_e);
#pragma unroll
  for (int j = 0; j < 16; j++) e1[j] = exp2_hw(e1[j] - m_e);
  float sm[8];
#pragma unroll
  for (int j = 0; j < 8; j++) sm[j] = (e0[j] + e0[j + 8]) + (e1[j] + e1[j + 8]);
#pragma unroll
  for (int j = 0; j < 4; j++) sm[j] += sm[j + 4];
  float lt = (sm[0] + sm[1]) + (sm[2] + sm[3]);
  lt += __shfl_xor(lt, 32);
  l_run += lt;

  unsigned W0[8], W1[8];
#pragma unroll
  for (int j = 0; j < 8; j++) {
    W0[j] = cvt_pk_bf16(e0[2 * j], e0[2 * j + 1]);
    W1[j] = cvt_pk_bf16(e1[2 * j], e1[2 * j + 1]);
  }
  u16x8 pa[4];
#pragma unroll
  for (int c = 0; c < 2; c++) {
    unsigned a0 = W0[4 * c], b0 = W0[4 * c + 2];
    unsigned a1 = W0[4 * c + 1], b1 = W0[4 * c + 3];
    asm("v_permlane32_swap_b32 %0, %1" : "+v"(a0), "+v"(b0));
    asm("v_permlane32_swap_b32 %0, %1" : "+v"(a1), "+v"(b1));
    union { unsigned u[4]; u16x8 v; } pk_;
    pk_.u[0] = a0; pk_.u[1] = a1; pk_.u[2] = b0; pk_.u[3] = b1;
    pa[c] = pk_.v;
  }
#pragma unroll
  for (int c = 0; c < 2; c++) {
    unsigned a0 = W1[4 * c], b0 = W1[4 * c + 2];
    unsigned a1 = W1[4 * c + 1], b1 = W1[4 * c + 3];
    asm("v_permlane32_swap_b32 %0, %1" : "+v"(a0), "+v"(b0));
    asm("v_permlane32_swap_b32 %0, %1" : "+v"(a1), "+v"(b1));
    union { unsigned u[4]; u16x8 v; } pk_;
    pk_.u[0] = a0; pk_.u[1] = a1; pk_.u[2] = b0; pk_.u[3] = b1;
    pa[2 + c] = pk_.v;
  }

#pragma unroll
  for (int cc = 0; cc < 4; cc++) {
    o0 = mfma32(pa[cc], vf[cc], o0);
    o1 = mfma32(pa[cc], vf[4 + cc], o1);
  }
}

__global__ __launch_bounds__(256, 5) void attn_fwd(
    const u16* __restrict__ Q, const u16* __restrict__ K,
    const u16* __restrict__ VT, u16* __restrict__ y) {
  __shared__ __align__(16) float tbl[N_];
  __shared__ __align__(16) float xldsa[4][32];

  const int bid0 = blockIdx.x;
  const int bid = (bid0 & 7) * 128 + (bid0 >> 3);  // XCD-chunked swizzle
  const int bh = bid >> 4;
  const int qt = bid & 15;
  const int t = threadIdx.x, w = t >> 6, lane = t & 63;
  const int ql = lane & 31;
  const int h = lane >> 5;
  const float L2E = 1.44269504088896340736f;

#pragma unroll
  for (int i = 0; i < 8; i++) {
    int k = i * 256 + t;
    float tt = (float)k * (1.0f / 2047.0f) - 0.5f;
    tbl[k] = -10.0f * L2E * tt * tt;
  }
  __syncthreads();

  const int q0 = qt * 128 + w * 32;
  const u16* Qb = Q + (size_t)bh * (N_ * D_);
  const u16* Kb = K + (size_t)bh * (N_ * D_);
  const u16* Vb = VT + (size_t)bh * (D_ * N_);
  float* xlds = xldsa[w];

  u16x8 qf[4];
#pragma unroll
  for (int s = 0; s < 4; s++)
    qf[s] = *(const u16x8*)(Qb + (size_t)(q0 + ql) * D_ + s * 16 + h * 8);

  f32x16 o0 = {}, o1 = {};
  float m_e = -INFINITY, l_run = 0.f;

  u16x8 kA[8], kB[8], vC[8];
  load_k(Kb, 0, lane, kA);

  for (int k0 = 0; k0 < N_; k0 += 128) {
    load_k(Kb, k0 + 64, lane, kB);
    load_v(Vb, k0, lane, vC);
    attn_tile(k0, tbl, xlds, kA, vC, qf, o0, o1, m_e, l_run, ql, h);
    if (k0 + 128 < N_)
      load_k(Kb, k0 + 128, lane, kA);
    load_v(Vb, k0 + 64, lane, vC);
    attn_tile(k0 + 64, tbl, xlds, kB, vC, qf, o0, o1, m_e, l_run, ql, h);
  }

  float linv = 1.0f / l_run;
  xlds[ql] = linv;
  const int b = bh >> 4, hh = bh & 15;
#pragma unroll
  for (int g2 = 0; g2 < 4; g2++) {
    f32x4 r4 = *(const f32x4*)&xlds[8 * g2 + 4 * h];
#pragma unroll
    for (int jj = 0; jj < 4; jj++) {
      int q = q0 + 8 * g2 + 4 * h + jj;
      size_t base = ((size_t)b * N_ + q) * C_ + hh * 64;
      y[base + ql] = f2bf(o0[g2 * 4 + jj] * r4[jj]);
      y[base + 32 + ql] = f2bf(o1[g2 * 4 + jj] * r4[jj]);
    }
  }
}

// ---------------- host launch ----------------
extern "C" void kernel_launch(void* const* d_in, const int* in_sizes, int n_in,
                              void* d_out, int out_size, void* d_ws, size_t ws_size,
                              hipStream_t stream) {
  (void)in_sizes; (void)n_in; (void)out_size; (void)ws_size;
  const float* q_in = (const float*)d_in[0];
  const float* k_in = (const float*)d_in[1];
  const float* v_in = (const float*)d_in[2];
  const float* Wq = (const float*)d_in[3];
  const float* bq = (const float*)d_in[4];
  const float* Wk = (const float*)d_in[5];
  const float* bk = (const float*)d_in[6];
  const float* Wv = (const float*)d_in[7];
  const float* bv = (const float*)d_in[8];
  const float* Wp = (const float*)d_in[9];
  const float* bp = (const float*)d_in[10];

  char* ws = (char*)d_ws;
  const size_t SZ_X = (size_t)8192 * 1024 * sizeof(u16);  // 16 MiB
  const size_t SZ_W = (size_t)1024 * 1024 * sizeof(u16);  // 2 MiB
  u16* Xq = (u16*)(ws);
  u16* Xk = (u16*)(ws + SZ_X);
  u16* Xv = (u16*)(ws + 2 * SZ_X);
  u16* Qb = (u16*)(ws + 3 * SZ_X);
  u16* Kb = (u16*)(ws + 4 * SZ_X);
  u16* VT = (u16*)(ws + 5 * SZ_X);
  u16* WqT = (u16*)(ws + 6 * SZ_X);
  u16* WkT = (u16*)(ws + 6 * SZ_X + SZ_W);
  u16* WvT = (u16*)(ws + 6 * SZ_X + 2 * SZ_W);
  u16* WpT = (u16*)(ws + 6 * SZ_X + 3 * SZ_W);
  u16* Y = Xq;  // reuse: Xq dead after QKV GEMMs

  convert_x3<<<dim3(8192, 3), 256, 0, stream>>>(q_in, k_in, v_in, Xq, Xk, Xv);
  transpose_convert_w4<<<dim3(256, 4), 256, 0, stream>>>(Wq, Wk, Wv, Wp, WqT, WkT,
                                                         WvT, WpT);

  gemm_qkv<<<dim3(512, 3), 256, 0, stream>>>(Xq, Xk, Xv, WqT, WkT, WvT, bq, bk, bv,
                                             Qb, Kb, VT);

  attn_fwd<<<1024, 256, 0, stream>>>(Qb, Kb, VT, Y);

  gemm_proj<<<512, 256, 0, stream>>>(Y, WpT, bp, (float*)d_out);
}

// Round 14
// 236.300 us; speedup vs baseline: 2.8222x; 2.8222x over previous
//
#include <hip/hip_runtime.h>
#include <stdint.h>

typedef unsigned short u16;
typedef float f32x4 __attribute__((ext_vector_type(4)));
typedef float f32x16 __attribute__((ext_vector_type(16)));
typedef __bf16 bf16x8 __attribute__((ext_vector_type(8)));
typedef u16 u16x8 __attribute__((ext_vector_type(8)));
typedef u16 u16x4 __attribute__((ext_vector_type(4)));

#define B_ 4
#define N_ 2048
#define C_ 1024
#define H_ 16
#define D_ 64

__device__ __forceinline__ u16 f2bf(float f) {
  unsigned u = __builtin_bit_cast(unsigned, f);
  u += 0x7FFFu + ((u >> 16) & 1u);
  return (u16)(u >> 16);
}
__device__ __forceinline__ float bf2f(u16 h) {
  unsigned u = ((unsigned)h) << 16;
  return __builtin_bit_cast(float, u);
}
__device__ __forceinline__ f32x4 mfma16(u16x8 a, u16x8 b, f32x4 c) {
  return __builtin_amdgcn_mfma_f32_16x16x32_bf16(
      __builtin_bit_cast(bf16x8, a), __builtin_bit_cast(bf16x8, b), c, 0, 0, 0);
}
__device__ __forceinline__ f32x16 mfma32(u16x8 a, u16x8 b, f32x16 c) {
  return __builtin_amdgcn_mfma_f32_32x32x16_bf16(
      __builtin_bit_cast(bf16x8, a), __builtin_bit_cast(bf16x8, b), c, 0, 0, 0);
}
__device__ __forceinline__ void gload_lds16(const void* g, void* l) {
  __builtin_amdgcn_global_load_lds(
      (const __attribute__((address_space(1))) void*)g,
      (__attribute__((address_space(3))) void*)l, 16, 0, 0);
}
__device__ __forceinline__ float exp2_hw(float x) {
  return __builtin_amdgcn_exp2f(x);
}
__device__ __forceinline__ unsigned cvt_pk_bf16(float lo, float hi) {
  unsigned d;
  asm("v_cvt_pk_bf16_f32 %0, %1, %2" : "=v"(d) : "v"(lo), "v"(hi));
  return d;
}

// ---------------- fp32 -> bf16 convert (3 tensors, one launch) ----------------
__global__ __launch_bounds__(256) void convert_x3(
    const float* __restrict__ a, const float* __restrict__ b,
    const float* __restrict__ c, u16* __restrict__ oa, u16* __restrict__ ob,
    u16* __restrict__ oc) {
  const float* in = blockIdx.y == 0 ? a : (blockIdx.y == 1 ? b : c);
  u16* out = blockIdx.y == 0 ? oa : (blockIdx.y == 1 ? ob : oc);
  int i = blockIdx.x * 256 + threadIdx.x;
  f32x4 v = *(const f32x4*)(in + (size_t)i * 4);
  u16x4 o;
#pragma unroll
  for (int j = 0; j < 4; j++) o[j] = f2bf(v[j]);
  *(u16x4*)(out + (size_t)i * 4) = o;
}

// -------- W [K][N] fp32 -> W^T [N][K] bf16, 4 weights in one launch --------
__global__ __launch_bounds__(256) void transpose_convert_w4(
    const float* __restrict__ w0, const float* __restrict__ w1,
    const float* __restrict__ w2, const float* __restrict__ w3,
    u16* __restrict__ o0, u16* __restrict__ o1, u16* __restrict__ o2,
    u16* __restrict__ o3) {
  const float* in = blockIdx.y == 0 ? w0
                    : blockIdx.y == 1 ? w1
                    : blockIdx.y == 2 ? w2 : w3;
  u16* out = blockIdx.y == 0 ? o0 : blockIdx.y == 1 ? o1 : blockIdx.y == 2 ? o2 : o3;
  __shared__ float tile[64][65];
  const int t = threadIdx.x;
  const int bx = blockIdx.x;
  const int tr = (bx >> 4) << 6;
  const int tc = (bx & 15) << 6;
#pragma unroll
  for (int i = 0; i < 16; i++) {
    int idx = i * 256 + t;
    int rr = idx >> 6, cc = idx & 63;
    tile[rr][cc] = in[(size_t)(tr + rr) * C_ + tc + cc];
  }
  __syncthreads();
#pragma unroll
  for (int i = 0; i < 16; i++) {
    int idx = i * 256 + t;
    int rr = idx >> 6, cc = idx & 63;
    out[(size_t)(tc + rr) * C_ + tr + cc] = f2bf(tile[cc][rr]);
  }
}

// ----- merged QKV GEMM: 128x128x64, BK=64, T2 swizzle (R6-verified loop) -----
__global__ __launch_bounds__(256) void gemm_qkv(
    const u16* __restrict__ Xq, const u16* __restrict__ Xk,
    const u16* __restrict__ Xv, const u16* __restrict__ WqT,
    const u16* __restrict__ WkT, const u16* __restrict__ WvT,
    const float* __restrict__ bq, const float* __restrict__ bk,
    const float* __restrict__ bv_, u16* __restrict__ Qb, u16* __restrict__ Kb,
    u16* __restrict__ VT) {
  __shared__ u16 lA[128 * 64];
  __shared__ u16 lB[128 * 64];

  const int sel = blockIdx.y;
  const u16* A = sel == 0 ? Xq : sel == 1 ? Xk : Xv;
  const u16* BT = sel == 0 ? WqT : sel == 1 ? WkT : WvT;
  const float* bias = sel == 0 ? bq : sel == 1 ? bk : bv_;

  const int K = 1024;
  const int t = threadIdx.x;
  const int w = t >> 6;
  const int lane = t & 63;
  const int g = lane >> 4;
  const int r = lane & 15;
  const int tm = blockIdx.x >> 3;
  const int tn = blockIdx.x & 7;
  const int m0 = tm << 7;
  const int n0 = tn << 7;
  const int wm = (w >> 1) << 6;
  const int wn = (w & 1) << 6;

  const int srow = t >> 3;
  const int scol = ((t & 7) ^ (srow & 7)) << 3;

  f32x4 acc[4][4] = {};

  for (int k0 = 0; k0 < K; k0 += 64) {
    __syncthreads();
    {
      const u16* gA = A + (size_t)(m0 + srow) * K + (k0 + scol);
      const u16* gB = BT + (size_t)(n0 + srow) * K + (k0 + scol);
#pragma unroll
      for (int p = 0; p < 4; p++) {
        gload_lds16(gA + (size_t)(p * 32) * K, (char*)lA + (p << 12) + (w << 10));
        gload_lds16(gB + (size_t)(p * 32) * K, (char*)lB + (p << 12) + (w << 10));
      }
    }
    asm volatile("s_waitcnt vmcnt(0)" ::: "memory");
    __syncthreads();

    const int rx = (r & 7) << 4;
#pragma unroll
    for (int kk = 0; kk < 2; kk++) {
      u16x8 af[4], bfv[4];
#pragma unroll
      for (int i = 0; i < 4; i++) {
        int rowa = wm + i * 16 + r;
        af[i] = *(const u16x8*)((const char*)lA + (rowa << 7) +
                                (((kk << 6) + (g << 4)) ^ rx));
      }
#pragma unroll
      for (int i = 0; i < 4; i++) {
        int rowb = wn + i * 16 + r;
        bfv[i] = *(const u16x8*)((const char*)lB + (rowb << 7) +
                                 (((kk << 6) + (g << 4)) ^ rx));
      }
#pragma unroll
      for (int mi = 0; mi < 4; mi++)
#pragma unroll
        for (int ni = 0; ni < 4; ni++)
          acc[mi][ni] = mfma16(af[mi], bfv[ni], acc[mi][ni]);
    }
  }

  float bv[4];
#pragma unroll
  for (int ni = 0; ni < 4; ni++) bv[ni] = bias[n0 + wn + ni * 16 + r];

  if (sel == 0) {  // Q: [B,H,N,D], scale 1/sqrt(D)
#pragma unroll
    for (int mi = 0; mi < 4; mi++)
#pragma unroll
      for (int ni = 0; ni < 4; ni++)
#pragma unroll
        for (int j = 0; j < 4; j++) {
          int gm = m0 + wm + mi * 16 + g * 4 + j;
          int gn = n0 + wn + ni * 16 + r;
          float v = (acc[mi][ni][j] + bv[ni]) * 0.125f;
          int b = gm >> 11, n = gm & 2047, h = gn >> 6, d = gn & 63;
          Qb[((((size_t)b * H_ + h) * N_ + n) << 6) + d] = f2bf(v);
        }
  } else if (sel == 1) {  // K' fragment-ready
#pragma unroll
    for (int mi = 0; mi < 4; mi++)
#pragma unroll
      for (int ni = 0; ni < 4; ni++)
#pragma unroll
        for (int j = 0; j < 4; j++) {
          int gm = m0 + wm + mi * 16 + g * 4 + j;
          int gn = n0 + wn + ni * 16 + r;
          float v = acc[mi][ni][j] + bv[ni];
          int b = gm >> 11, n = gm & 2047, h = gn >> 6, d = gn & 63;
          size_t off = (((size_t)(b * H_ + h)) << 17) + ((size_t)(n >> 5) << 11) +
                       ((d >> 4) << 9) + ((((d >> 3) & 1) << 5) + (n & 31)) * 8 + (d & 7);
          Kb[off] = f2bf(v);
        }
  } else {  // V' fragment-ready
#pragma unroll
    for (int mi = 0; mi < 4; mi++)
#pragma unroll
      for (int ni = 0; ni < 4; ni++) {
        int gm0 = m0 + wm + mi * 16 + g * 4;
        int gn = n0 + wn + ni * 16 + r;
        int b = gm0 >> 11, n = gm0 & 2047, h = gn >> 6, d = gn & 63;
        size_t off = (((size_t)(b * H_ + h)) << 17) + ((size_t)(n >> 6) << 12) +
                     ((size_t)((d >> 5) * 4 + ((n >> 4) & 3)) << 9) +
                     ((((n >> 3) & 1) << 5) + (d & 31)) * 8 + (n & 7);
        u16x4 pk;
#pragma unroll
        for (int j = 0; j < 4; j++) pk[j] = f2bf(acc[mi][ni][j] + bv[ni]);
        *(u16x4*)&VT[off] = pk;
      }
  }
}

// ------- final projection GEMM: 128x128x64, BK=64, T2 swizzle, fp32 out ------
__global__ __launch_bounds__(256) void gemm_proj(
    const u16* __restrict__ A, const u16* __restrict__ BT,
    const float* __restrict__ bias, float* __restrict__ out) {
  __shared__ u16 lA[128 * 64];
  __shared__ u16 lB[128 * 64];

  const int K = 1024, N = 1024;
  const int t = threadIdx.x;
  const int w = t >> 6;
  const int lane = t & 63;
  const int g = lane >> 4;
  const int r = lane & 15;
  const int tm = blockIdx.x >> 3;
  const int tn = blockIdx.x & 7;
  const int m0 = tm << 7;
  const int n0 = tn << 7;
  const int wm = (w >> 1) << 6;
  const int wn = (w & 1) << 6;

  const int srow = t >> 3;
  const int scol = ((t & 7) ^ (srow & 7)) << 3;

  f32x4 acc[4][4] = {};

  for (int k0 = 0; k0 < K; k0 += 64) {
    __syncthreads();
    {
      const u16* gA = A + (size_t)(m0 + srow) * K + (k0 + scol);
      const u16* gB = BT + (size_t)(n0 + srow) * K + (k0 + scol);
#pragma unroll
      for (int p = 0; p < 4; p++) {
        gload_lds16(gA + (size_t)(p * 32) * K, (char*)lA + (p << 12) + (w << 10));
        gload_lds16(gB + (size_t)(p * 32) * K, (char*)lB + (p << 12) + (w << 10));
      }
    }
    asm volatile("s_waitcnt vmcnt(0)" ::: "memory");
    __syncthreads();

    const int rx = (r & 7) << 4;
#pragma unroll
    for (int kk = 0; kk < 2; kk++) {
      u16x8 af[4], bfv[4];
#pragma unroll
      for (int i = 0; i < 4; i++) {
        int rowa = wm + i * 16 + r;
        af[i] = *(const u16x8*)((const char*)lA + (rowa << 7) +
                                (((kk << 6) + (g << 4)) ^ rx));
      }
#pragma unroll
      for (int i = 0; i < 4; i++) {
        int rowb = wn + i * 16 + r;
        bfv[i] = *(const u16x8*)((const char*)lB + (rowb << 7) +
                                 (((kk << 6) + (g << 4)) ^ rx));
      }
#pragma unroll
      for (int mi = 0; mi < 4; mi++)
#pragma unroll
        for (int ni = 0; ni < 4; ni++)
          acc[mi][ni] = mfma16(af[mi], bfv[ni], acc[mi][ni]);
    }
  }

  float bv[4];
#pragma unroll
  for (int ni = 0; ni < 4; ni++) bv[ni] = bias[n0 + wn + ni * 16 + r];

#pragma unroll
  for (int mi = 0; mi < 4; mi++)
#pragma unroll
    for (int ni = 0; ni < 4; ni++)
#pragma unroll
      for (int j = 0; j < 4; j++) {
        int gm = m0 + wm + mi * 16 + g * 4 + j;
        int gn = n0 + wn + ni * 16 + r;
        out[(size_t)gm * N + gn] = acc[mi][ni][j] + bv[ni];
      }
}

// ---------------- flash attention: K dbuf, V single-buffered (R12-verified) ---
// Q: [B,H,N,D] bf16 (pre-scaled); K',V': fragment-ready (see gemm epilogues).
// VGPR 108 = 4 waves/SIMD is this design's constrained optimum:
//   R8/R9: +VGPR crosses the 128 cliff (-25..58%);  R13: forcing 5 waves/SIMD
//   (102-reg cap) spills the ~108-reg architectural state to scratch (4.4x).
// Do NOT add launch bounds or live state to this kernel.
__device__ __forceinline__ void load_k(const u16* __restrict__ Kb, int k0,
                                       int lane, u16x8 (&kf)[8]) {
  const u16* pK = Kb + ((size_t)(k0 >> 5) << 11) + lane * 8;
#pragma unroll
  for (int s = 0; s < 4; s++) {
    kf[s] = *(const u16x8*)(pK + (s << 9));
    kf[4 + s] = *(const u16x8*)(pK + 2048 + (s << 9));
  }
}
__device__ __forceinline__ void load_v(const u16* __restrict__ Vb, int k0,
                                       int lane, u16x8 (&vf)[8]) {
  const u16* pV = Vb + ((size_t)(k0 >> 6) << 12) + ((k0 & 32) ? 256 : 0) + lane * 8;
#pragma unroll
  for (int c = 0; c < 8; c++) vf[c] = *(const u16x8*)(pV + (c << 9));
}

__device__ __forceinline__ void attn_tile(int k0, const float* __restrict__ tbl,
                                          float* __restrict__ xlds,
                                          const u16x8 (&kf)[8], const u16x8 (&vf)[8],
                                          const u16x8 (&qf)[4], f32x16& o0, f32x16& o1,
                                          float& m_e, float& l_run, int ql, int h) {
  const float L2E = 1.44269504088896340736f;
  f32x16 st0 = {}, st1 = {};
#pragma unroll
  for (int s = 0; s < 4; s++) st0 = mfma32(kf[s], qf[s], st0);
#pragma unroll
  for (int s = 0; s < 4; s++) st1 = mfma32(kf[4 + s], qf[s], st1);

  float e0[16], e1[16];
#pragma unroll
  for (int g2 = 0; g2 < 4; g2++) {
    f32x4 t0 = *(const f32x4*)&tbl[k0 + 8 * g2 + 4 * h];
    f32x4 t1 = *(const f32x4*)&tbl[k0 + 32 + 8 * g2 + 4 * h];
#pragma unroll
    for (int jj = 0; jj < 4; jj++) {
      e0[g2 * 4 + jj] = fmaf(st0[g2 * 4 + jj], L2E, t0[jj]);
      e1[g2 * 4 + jj] = fmaf(st1[g2 * 4 + jj], L2E, t1[jj]);
    }
  }
  float mx[8];
#pragma unroll
  for (int j = 0; j < 8; j++)
    mx[j] = fmaxf(fmaxf(e0[j], e0[j + 8]), fmaxf(e1[j], e1[j + 8]));
#pragma unroll
  for (int j = 0; j < 4; j++) mx[j] = fmaxf(mx[j], mx[j + 4]);
  float pmax = fmaxf(fmaxf(mx[0], mx[1]), fmaxf(mx[2], mx[3]));
  pmax = fmaxf(pmax, __shfl_xor(pmax, 32));

  if (!__all(pmax <= m_e + 8.0f)) {
    float m_new = fmaxf(m_e, pmax);
    float resc = exp2_hw(m_e - m_new);
    xlds[ql] = resc;
#pragma unroll
    for (int g2 = 0; g2 < 4; g2++) {
      f32x4 r4 = *(const f32x4*)&xlds[8 * g2 + 4 * h];
#pragma unroll
      for (int jj = 0; jj < 4; jj++) {
        o0[g2 * 4 + jj] *= r4[jj];
        o1[g2 * 4 + jj] *= r4[jj];
      }
    }
    l_run *= resc;
    m_e = m_new;
  }

#pragma unroll
  for (int j = 0; j < 16; j++) e0[j] = exp2_hw(e0[j] - m_e);
#pragma unroll
  for (int j = 0; j < 16; j++) e1[j] = exp2_hw(e1[j] - m_e);
  float sm[8];
#pragma unroll
  for (int j = 0; j < 8; j++) sm[j] = (e0[j] + e0[j + 8]) + (e1[j] + e1[j + 8]);
#pragma unroll
  for (int j = 0; j < 4; j++) sm[j] += sm[j + 4];
  float lt = (sm[0] + sm[1]) + (sm[2] + sm[3]);
  lt += __shfl_xor(lt, 32);
  l_run += lt;

  unsigned W0[8], W1[8];
#pragma unroll
  for (int j = 0; j < 8; j++) {
    W0[j] = cvt_pk_bf16(e0[2 * j], e0[2 * j + 1]);
    W1[j] = cvt_pk_bf16(e1[2 * j], e1[2 * j + 1]);
  }
  u16x8 pa[4];
#pragma unroll
  for (int c = 0; c < 2; c++) {
    unsigned a0 = W0[4 * c], b0 = W0[4 * c + 2];
    unsigned a1 = W0[4 * c + 1], b1 = W0[4 * c + 3];
    asm("v_permlane32_swap_b32 %0, %1" : "+v"(a0), "+v"(b0));
    asm("v_permlane32_swap_b32 %0, %1" : "+v"(a1), "+v"(b1));
    union { unsigned u[4]; u16x8 v; } pk_;
    pk_.u[0] = a0; pk_.u[1] = a1; pk_.u[2] = b0; pk_.u[3] = b1;
    pa[c] = pk_.v;
  }
#pragma unroll
  for (int c = 0; c < 2; c++) {
    unsigned a0 = W1[4 * c], b0 = W1[4 * c + 2];
    unsigned a1 = W1[4 * c + 1], b1 = W1[4 * c + 3];
    asm("v_permlane32_swap_b32 %0, %1" : "+v"(a0), "+v"(b0));
    asm("v_permlane32_swap_b32 %0, %1" : "+v"(a1), "+v"(b1));
    union { unsigned u[4]; u16x8 v; } pk_;
    pk_.u[0] = a0; pk_.u[1] = a1; pk_.u[2] = b0; pk_.u[3] = b1;
    pa[2 + c] = pk_.v;
  }

#pragma unroll
  for (int cc = 0; cc < 4; cc++) {
    o0 = mfma32(pa[cc], vf[cc], o0);
    o1 = mfma32(pa[cc], vf[4 + cc], o1);
  }
}

__global__ __launch_bounds__(256) void attn_fwd(
    const u16* __restrict__ Q, const u16* __restrict__ K,
    const u16* __restrict__ VT, u16* __restrict__ y) {
  __shared__ __align__(16) float tbl[N_];
  __shared__ __align__(16) float xldsa[4][32];

  const int bid0 = blockIdx.x;
  const int bid = (bid0 & 7) * 128 + (bid0 >> 3);  // XCD-chunked swizzle
  const int bh = bid >> 4;
  const int qt = bid & 15;
  const int t = threadIdx.x, w = t >> 6, lane = t & 63;
  const int ql = lane & 31;
  const int h = lane >> 5;
  const float L2E = 1.44269504088896340736f;

#pragma unroll
  for (int i = 0; i < 8; i++) {
    int k = i * 256 + t;
    float tt = (float)k * (1.0f / 2047.0f) - 0.5f;
    tbl[k] = -10.0f * L2E * tt * tt;
  }
  __syncthreads();

  const int q0 = qt * 128 + w * 32;
  const u16* Qb = Q + (size_t)bh * (N_ * D_);
  const u16* Kb = K + (size_t)bh * (N_ * D_);
  const u16* Vb = VT + (size_t)bh * (D_ * N_);
  float* xlds = xldsa[w];

  u16x8 qf[4];
#pragma unroll
  for (int s = 0; s < 4; s++)
    qf[s] = *(const u16x8*)(Qb + (size_t)(q0 + ql) * D_ + s * 16 + h * 8);

  f32x16 o0 = {}, o1 = {};
  float m_e = -INFINITY, l_run = 0.f;

  u16x8 kA[8], kB[8], vC[8];
  load_k(Kb, 0, lane, kA);

  for (int k0 = 0; k0 < N_; k0 += 128) {
    load_k(Kb, k0 + 64, lane, kB);
    load_v(Vb, k0, lane, vC);
    attn_tile(k0, tbl, xlds, kA, vC, qf, o0, o1, m_e, l_run, ql, h);
    if (k0 + 128 < N_)
      load_k(Kb, k0 + 128, lane, kA);
    load_v(Vb, k0 + 64, lane, vC);
    attn_tile(k0 + 64, tbl, xlds, kB, vC, qf, o0, o1, m_e, l_run, ql, h);
  }

  float linv = 1.0f / l_run;
  xlds[ql] = linv;
  const int b = bh >> 4, hh = bh & 15;
#pragma unroll
  for (int g2 = 0; g2 < 4; g2++) {
    f32x4 r4 = *(const f32x4*)&xlds[8 * g2 + 4 * h];
#pragma unroll
    for (int jj = 0; jj < 4; jj++) {
      int q = q0 + 8 * g2 + 4 * h + jj;
      size_t base = ((size_t)b * N_ + q) * C_ + hh * 64;
      y[base + ql] = f2bf(o0[g2 * 4 + jj] * r4[jj]);
      y[base + 32 + ql] = f2bf(o1[g2 * 4 + jj] * r4[jj]);
    }
  }
}

// ---------------- host launch ----------------
extern "C" void kernel_launch(void* const* d_in, const int* in_sizes, int n_in,
                              void* d_out, int out_size, void* d_ws, size_t ws_size,
                              hipStream_t stream) {
  (void)in_sizes; (void)n_in; (void)out_size; (void)ws_size;
  const float* q_in = (const float*)d_in[0];
  const float* k_in = (const float*)d_in[1];
  const float* v_in = (const float*)d_in[2];
  const float* Wq = (const float*)d_in[3];
  const float* bq = (const float*)d_in[4];
  const float* Wk = (const float*)d_in[5];
  const float* bk = (const float*)d_in[6];
  const float* Wv = (const float*)d_in[7];
  const float* bv = (const float*)d_in[8];
  const float* Wp = (const float*)d_in[9];
  const float* bp = (const float*)d_in[10];

  char* ws = (char*)d_ws;
  const size_t SZ_X = (size_t)8192 * 1024 * sizeof(u16);  // 16 MiB
  const size_t SZ_W = (size_t)1024 * 1024 * sizeof(u16);  // 2 MiB
  u16* Xq = (u16*)(ws);
  u16* Xk = (u16*)(ws + SZ_X);
  u16* Xv = (u16*)(ws + 2 * SZ_X);
  u16* Qb = (u16*)(ws + 3 * SZ_X);
  u16* Kb = (u16*)(ws + 4 * SZ_X);
  u16* VT = (u16*)(ws + 5 * SZ_X);
  u16* WqT = (u16*)(ws + 6 * SZ_X);
  u16* WkT = (u16*)(ws + 6 * SZ_X + SZ_W);
  u16* WvT = (u16*)(ws + 6 * SZ_X + 2 * SZ_W);
  u16* WpT = (u16*)(ws + 6 * SZ_X + 3 * SZ_W);
  u16* Y = Xq;  // reuse: Xq dead after QKV GEMMs

  convert_x3<<<dim3(8192, 3), 256, 0, stream>>>(q_in, k_in, v_in, Xq, Xk, Xv);
  transpose_convert_w4<<<dim3(256, 4), 256, 0, stream>>>(Wq, Wk, Wv, Wp, WqT, WkT,
                                                         WvT, WpT);

  gemm_qkv<<<dim3(512, 3), 256, 0, stream>>>(Xq, Xk, Xv, WqT, WkT, WvT, bq, bk, bv,
                                             Qb, Kb, VT);

  attn_fwd<<<1024, 256, 0, stream>>>(Qb, Kb, VT, Y);

  gemm_proj<<<512, 256, 0, stream>>>(Y, WpT, bp, (float*)d_out);
}